// Round 4
// baseline (857.714 us; speedup 1.0000x reference)
//
#include <hip/hip_runtime.h>

typedef __bf16 bf16;
typedef bf16 bf16x8 __attribute__((ext_vector_type(8)));
typedef bf16 bf16x4 __attribute__((ext_vector_type(4)));
typedef float f32x4 __attribute__((ext_vector_type(4)));

#define MFMA16(a, b, c) __builtin_amdgcn_mfma_f32_16x16x32_bf16((a), (b), (c), 0, 0, 0)

// Problem constants: B=2, S=2048, D=1024, H=16, dk=64
// ws layout (bf16 elems unless noted):
//   qh  [2][2048][1024]          offset 0        (8 MB)
//   kh  [2][2048][1024]          +4194304        (8 MB)
//   vt  [2][16][64][2048]        +8388608        (8 MB)  (V transposed per head)
//   ctx [2][2048][1024]          +12582912       (8 MB)
//   pm  uint32 [2][2048][64]     +16777216 elems (1 MB)  (bit-packed mask)

// ---------------------------------------------------------------- mask pack
__global__ __launch_bounds__(256) void pack_mask_kernel(const int* __restrict__ mask,
                                                        unsigned* __restrict__ pm) {
  int idx = blockIdx.x * 256 + threadIdx.x;  // 0 .. 2*2048*64
  const int4* m4 = reinterpret_cast<const int4*>(mask) + (size_t)idx * 8;
  unsigned w = 0;
#pragma unroll
  for (int i = 0; i < 8; ++i) {
    int4 v = m4[i];
    w |= (v.x ? 1u : 0u) << (i * 4 + 0);
    w |= (v.y ? 1u : 0u) << (i * 4 + 1);
    w |= (v.z ? 1u : 0u) << (i * 4 + 2);
    w |= (v.w ? 1u : 0u) << (i * 4 + 3);
  }
  pm[idx] = w;
}

// ---------------------------------------------------------------- GEMM core
// Y[M=4096][N=1024] = A[4096][1024] @ W[1024][1024]^T + bias, bf16 MFMA.
// omode 0: bf16 row-major; 1: bf16 v-transposed [b][h][d][s]; 2: fp32 row-major.
__device__ __forceinline__ void cvt16(const float* __restrict__ src, bf16x8& p0, bf16x8& p1) {
  float4 v0 = ((const float4*)src)[0], v1 = ((const float4*)src)[1];
  float4 v2 = ((const float4*)src)[2], v3 = ((const float4*)src)[3];
  p0[0] = (bf16)v0.x; p0[1] = (bf16)v0.y; p0[2] = (bf16)v0.z; p0[3] = (bf16)v0.w;
  p0[4] = (bf16)v1.x; p0[5] = (bf16)v1.y; p0[6] = (bf16)v1.z; p0[7] = (bf16)v1.w;
  p1[0] = (bf16)v2.x; p1[1] = (bf16)v2.y; p1[2] = (bf16)v2.z; p1[3] = (bf16)v2.w;
  p1[4] = (bf16)v3.x; p1[5] = (bf16)v3.y; p1[6] = (bf16)v3.z; p1[7] = (bf16)v3.w;
}

template <bool ABF16>
__device__ __forceinline__ void gemm_core(const void* __restrict__ Aptr,
                                          const float* __restrict__ W,
                                          const float* __restrict__ bias,
                                          void* __restrict__ Out, int omode) {
  constexpr int K = 1024, N = 1024;
  __shared__ bf16 As[128][72];
  __shared__ bf16 Bs[128][72];
  const int tid = threadIdx.x;
  const int l = tid & 63;
  const int wv = tid >> 6, wm = wv >> 1, wn = wv & 1;
  const int bm = blockIdx.x, bn = blockIdx.y;
  const int lr = l & 15, lg = l >> 4;

  f32x4 acc[4][4];
#pragma unroll
  for (int m = 0; m < 4; ++m)
#pragma unroll
    for (int n = 0; n < 4; ++n) acc[m][n] = (f32x4){0.f, 0.f, 0.f, 0.f};

  const int r0 = tid >> 2;           // 0..63
  const int c0 = (tid & 3) << 4;     // 0,16,32,48

  for (int k0 = 0; k0 < K; k0 += 64) {
#pragma unroll
    for (int hh = 0; hh < 2; ++hh) {
      const int row = r0 + hh * 64;
      if (ABF16) {
        const bf16* src = (const bf16*)Aptr + (size_t)(bm * 128 + row) * K + k0 + c0;
        *(bf16x8*)&As[row][c0] = *(const bf16x8*)src;
        *(bf16x8*)&As[row][c0 + 8] = *(const bf16x8*)(src + 8);
      } else {
        const float* src = (const float*)Aptr + (size_t)(bm * 128 + row) * K + k0 + c0;
        bf16x8 p0, p1;
        cvt16(src, p0, p1);
        *(bf16x8*)&As[row][c0] = p0;
        *(bf16x8*)&As[row][c0 + 8] = p1;
      }
      const float* wsrc = W + (size_t)(bn * 128 + row) * K + k0 + c0;
      bf16x8 q0, q1;
      cvt16(wsrc, q0, q1);
      *(bf16x8*)&Bs[row][c0] = q0;
      *(bf16x8*)&Bs[row][c0 + 8] = q1;
    }
    __syncthreads();
#pragma unroll
    for (int f = 0; f < 2; ++f) {
      bf16x8 am[4], bb[4];
#pragma unroll
      for (int m = 0; m < 4; ++m)
        am[m] = *(const bf16x8*)&As[wm * 64 + m * 16 + lr][f * 32 + lg * 8];
#pragma unroll
      for (int n = 0; n < 4; ++n)
        bb[n] = *(const bf16x8*)&Bs[wn * 64 + n * 16 + lr][f * 32 + lg * 8];
#pragma unroll
      for (int m = 0; m < 4; ++m)
#pragma unroll
        for (int n = 0; n < 4; ++n) acc[m][n] = MFMA16(am[m], bb[n], acc[m][n]);
    }
    __syncthreads();
  }

#pragma unroll
  for (int n = 0; n < 4; ++n) {
    const int col = bn * 128 + wn * 64 + n * 16 + lr;
    const float bv = bias[col];
#pragma unroll
    for (int m = 0; m < 4; ++m) {
      const int row0 = bm * 128 + wm * 64 + m * 16 + lg * 4;
      if (omode == 0) {
        bf16* O = (bf16*)Out;
#pragma unroll
        for (int j = 0; j < 4; ++j)
          O[(size_t)(row0 + j) * N + col] = (bf16)(acc[m][n][j] + bv);
      } else if (omode == 1) {
        bf16* O = (bf16*)Out;
        const int bq = row0 >> 11, srow = row0 & 2047;
        const int hid = col >> 6, d = col & 63;
        bf16x4 pk;
#pragma unroll
        for (int j = 0; j < 4; ++j) pk[j] = (bf16)(acc[m][n][j] + bv);
        *(bf16x4*)&O[(((size_t)(bq * 16 + hid) * 64 + d) << 11) + srow] = pk;
      } else {
        float* O = (float*)Out;
#pragma unroll
        for (int j = 0; j < 4; ++j)
          O[(size_t)(row0 + j) * N + col] = acc[m][n][j] + bv;
      }
    }
  }
}

__global__ __launch_bounds__(256, 2) void gemm_proj_kernel(
    const float* __restrict__ q, const float* __restrict__ k, const float* __restrict__ v,
    const float* __restrict__ Wq, const float* __restrict__ Wk, const float* __restrict__ Wv,
    const float* __restrict__ bq, const float* __restrict__ bk, const float* __restrict__ bv,
    bf16* __restrict__ qh, bf16* __restrict__ kh, bf16* __restrict__ vt) {
  const int z = blockIdx.z;
  const float* A = z == 0 ? q : z == 1 ? k : v;
  const float* W = z == 0 ? Wq : z == 1 ? Wk : Wv;
  const float* bi = z == 0 ? bq : z == 1 ? bk : bv;
  void* O = z == 0 ? (void*)qh : z == 1 ? (void*)kh : (void*)vt;
  gemm_core<false>(A, W, bi, O, z == 2 ? 1 : 0);
}

__global__ __launch_bounds__(256, 2) void gemm_out_kernel(const bf16* __restrict__ ctx,
                                                          const float* __restrict__ Wo,
                                                          const float* __restrict__ bo,
                                                          float* __restrict__ out) {
  gemm_core<true>(ctx, Wo, bo, out, 2);
}

// ---------------------------------------------------------------- attention
__device__ __forceinline__ void compute_scores(const bf16 (*Kt)[72], const bf16x8& aq0,
                                               const bf16x8& aq1,
                                               const unsigned (&mwa)[4][4], int lr, int lg,
                                               f32x4 (&sc)[8]) {
#pragma unroll
  for (int n = 0; n < 8; ++n) {
    f32x4 s = (f32x4){0.f, 0.f, 0.f, 0.f};
    bf16x8 bk0 = *(const bf16x8*)&Kt[n * 16 + lr][lg * 8];
    s = MFMA16(aq0, bk0, s);
    bf16x8 bk1 = *(const bf16x8*)&Kt[n * 16 + lr][32 + lg * 8];
    s = MFMA16(aq1, bk1, s);
#pragma unroll
    for (int j = 0; j < 4; ++j) {
      float sv = s[j] * 0.125f;  // 1/sqrt(64)
      if (!((mwa[j][n >> 1] >> (((n & 1) << 4) + lr)) & 1)) sv = -1e9f;
      s[j] = sv;
    }
    sc[n] = s;
  }
}

__global__ __launch_bounds__(256, 3) void attn_kernel(
    const bf16* __restrict__ qh, const bf16* __restrict__ kh, const bf16* __restrict__ vt,
    const unsigned* __restrict__ pm, float* __restrict__ scores, bf16* __restrict__ ctx) {
  __shared__ bf16 Kt[128][72];     // [key][d]
  __shared__ bf16 Vt[64][136];     // [d][key]
  __shared__ bf16 Pt[4][16][136];  // per-wave [q][key]

  const int tid = threadIdx.x, l = tid & 63, wv = tid >> 6;
  const int lr = l & 15, lg = l >> 4;
  const int qt = blockIdx.x, h = blockIdx.y, b = blockIdx.z;

  // Q fragments (A operand): row = lr, k-dim = head dim
  const int qrow_lane = qt * 64 + wv * 16 + lr;
  const bf16* qb = qh + ((size_t)(b * 2048 + qrow_lane)) * 1024 + h * 64 + lg * 8;
  const bf16x8 aq0 = *(const bf16x8*)qb;
  const bf16x8 aq1 = *(const bf16x8*)(qb + 32);

  const int qg0 = qt * 64 + wv * 16 + lg * 4;  // acc reg j -> q row qg0+j

  const int kr = tid >> 1, kc = (tid & 1) << 5;
  const int vr = tid >> 2, vc = (tid & 3) << 5;
  const bf16* khb = kh + ((size_t)(b * 2048)) * 1024 + h * 64;
  const bf16* vtb = vt + ((size_t)(b * 16 + h) * 64) * 2048;
  const unsigned* pmb = pm + (size_t)(b * 2048) * 64;

  float m_run[4], l_run[4];
#pragma unroll
  for (int j = 0; j < 4; ++j) { m_run[j] = -__builtin_inff(); l_run[j] = 0.f; }

  // ---------------- pass 1: online row max + sum(exp)
  for (int kt = 0; kt < 16; ++kt) {
    {
      const bf16* src = khb + (size_t)(kt * 128 + kr) * 1024 + kc;
#pragma unroll
      for (int i = 0; i < 4; ++i)
        *(bf16x8*)&Kt[kr][kc + i * 8] = *(const bf16x8*)(src + i * 8);
    }
    __syncthreads();
    unsigned mwa[4][4];
#pragma unroll
    for (int j = 0; j < 4; ++j) {
      uint4 u = *(const uint4*)&pmb[(size_t)(qg0 + j) * 64 + kt * 4];
      mwa[j][0] = u.x; mwa[j][1] = u.y; mwa[j][2] = u.z; mwa[j][3] = u.w;
    }
    f32x4 sc[8];
    compute_scores(Kt, aq0, aq1, mwa, lr, lg, sc);
#pragma unroll
    for (int j = 0; j < 4; ++j) {
      float t = sc[0][j];
#pragma unroll
      for (int n = 1; n < 8; ++n) t = fmaxf(t, sc[n][j]);
#pragma unroll
      for (int d = 1; d < 16; d <<= 1) t = fmaxf(t, __shfl_xor(t, d, 64));
      const float mn = fmaxf(m_run[j], t);
      float p = 0.f;
#pragma unroll
      for (int n = 0; n < 8; ++n) p += __expf(sc[n][j] - mn);
#pragma unroll
      for (int d = 1; d < 16; d <<= 1) p += __shfl_xor(p, d, 64);
      l_run[j] = l_run[j] * __expf(m_run[j] - mn) + p;
      m_run[j] = mn;
    }
    __syncthreads();
  }

  float inv_l[4];
#pragma unroll
  for (int j = 0; j < 4; ++j) inv_l[j] = 1.f / l_run[j];

  f32x4 oacc[4];
#pragma unroll
  for (int dt = 0; dt < 4; ++dt) oacc[dt] = (f32x4){0.f, 0.f, 0.f, 0.f};

  // ---------------- pass 2: recompute scores, emit probs, PV
  for (int kt = 0; kt < 16; ++kt) {
    {
      const bf16* src = khb + (size_t)(kt * 128 + kr) * 1024 + kc;
#pragma unroll
      for (int i = 0; i < 4; ++i)
        *(bf16x8*)&Kt[kr][kc + i * 8] = *(const bf16x8*)(src + i * 8);
      const bf16* vsrc = vtb + (size_t)vr * 2048 + kt * 128 + vc;
#pragma unroll
      for (int i = 0; i < 4; ++i)
        *(bf16x8*)&Vt[vr][vc + i * 8] = *(const bf16x8*)(vsrc + i * 8);
    }
    __syncthreads();
    unsigned mwa[4][4];
#pragma unroll
    for (int j = 0; j < 4; ++j) {
      uint4 u = *(const uint4*)&pmb[(size_t)(qg0 + j) * 64 + kt * 4];
      mwa[j][0] = u.x; mwa[j][1] = u.y; mwa[j][2] = u.z; mwa[j][3] = u.w;
    }
    f32x4 sc[8];
    compute_scores(Kt, aq0, aq1, mwa, lr, lg, sc);
#pragma unroll
    for (int n = 0; n < 8; ++n) {
#pragma unroll
      for (int j = 0; j < 4; ++j) {
        const float p = __expf(sc[n][j] - m_run[j]) * inv_l[j];
        scores[((size_t)(b * 2048 + qg0 + j) * 16 + h) * 2048 + kt * 128 + n * 16 + lr] = p;
        Pt[wv][lg * 4 + j][n * 16 + lr] = (bf16)p;
      }
    }
    // PV: A = P (row=q), B = V^T rows (col=d)
#pragma unroll
    for (int dt = 0; dt < 4; ++dt) {
#pragma unroll
      for (int ks = 0; ks < 4; ++ks) {
        bf16x8 ap = *(const bf16x8*)&Pt[wv][lr][ks * 32 + lg * 8];
        bf16x8 bvv = *(const bf16x8*)&Vt[dt * 16 + lr][ks * 32 + lg * 8];
        oacc[dt] = MFMA16(ap, bvv, oacc[dt]);
      }
    }
    __syncthreads();
  }

#pragma unroll
  for (int dt = 0; dt < 4; ++dt)
#pragma unroll
    for (int j = 0; j < 4; ++j)
      ctx[((size_t)(b * 2048 + qg0 + j)) * 1024 + h * 64 + dt * 16 + lr] = (bf16)oacc[dt][j];
}

// ---------------------------------------------------------------- launch
extern "C" void kernel_launch(void* const* d_in, const int* in_sizes, int n_in,
                              void* d_out, int out_size, void* d_ws, size_t ws_size,
                              hipStream_t stream) {
  const float* q = (const float*)d_in[0];
  const float* k = (const float*)d_in[1];
  const float* v = (const float*)d_in[2];
  const int* mask = (const int*)d_in[3];
  const float* Wq = (const float*)d_in[4];
  const float* bq = (const float*)d_in[5];
  const float* Wk = (const float*)d_in[6];
  const float* bk = (const float*)d_in[7];
  const float* Wv = (const float*)d_in[8];
  const float* bv = (const float*)d_in[9];
  const float* Wo = (const float*)d_in[10];
  const float* bo = (const float*)d_in[11];

  float* out = (float*)d_out;
  float* scores = out + (size_t)2 * 2048 * 1024;

  bf16* qh = (bf16*)d_ws;
  bf16* kh = qh + 4194304;
  bf16* vt = kh + 4194304;
  bf16* ctx = vt + 4194304;
  unsigned* pm = (unsigned*)(ctx + 4194304);

  pack_mask_kernel<<<dim3(1024), dim3(256), 0, stream>>>(mask, pm);
  gemm_proj_kernel<<<dim3(32, 8, 3), dim3(256), 0, stream>>>(q, k, v, Wq, Wk, Wv, bq, bk, bv,
                                                             qh, kh, vt);
  attn_kernel<<<dim3(32, 16, 2), dim3(256), 0, stream>>>(qh, kh, vt, pm, scores, ctx);
  gemm_out_kernel<<<dim3(32, 8), dim3(256), 0, stream>>>(ctx, Wo, bo, out);
}